// Round 12
// baseline (800.639 us; speedup 1.0000x reference)
//
#include <hip/hip_runtime.h>
#include <hip/hip_bf16.h>

// ---------------------------------------------------------------------------
// Transformer block, algebraically folded:
//   Wqk_h = Wq_h Wk_h^T   -> scores = scale*(LN1 Wqk_h + 1*(Wk_h bq_h)^T) LN1^T
//   Wvo_h = Wv_h Wo_h     -> x1 = x + sum_h P_h (LN1 Wvo_h) + (bo + sum_h bv_h Wo_h)
// P stored [s][h*1024+t], VO stored [e][h*1024+t] -> sum_h P_h VO_h is ONE
// GEMM with K=12288, split-K 4 into f32 partials + reduce4.
//
// GEMM core (this round): 128x128 tile, BK=32, RING-4 LDS (64 KiB), ONE
// barrier per K-step, counted vmcnt(8) (T4: loads span 3 iterations ~1500cyc
// > HBM latency), lgkmcnt(0)+sched_barrier(0) fence before MFMA (rule #18),
// setprio around MFMA, m204 XCD-bijective block swizzle. Linear LDS.
// ---------------------------------------------------------------------------

typedef __attribute__((ext_vector_type(8))) __bf16 bf16x8;
typedef __attribute__((ext_vector_type(4))) float f32x4;
typedef __attribute__((ext_vector_type(4))) float float4_t;
typedef __attribute__((ext_vector_type(4))) unsigned short ushort4_t;

#define DEV __device__ __forceinline__

DEV unsigned short f2bf(float f) {
    __hip_bfloat16 h = __float2bfloat16(f);
    return *reinterpret_cast<unsigned short*>(&h);
}
DEV float bf2f(unsigned short u) {
    return __uint_as_float(((unsigned int)u) << 16);
}

DEV void gld16(const void* g, void* l) {
    __builtin_amdgcn_global_load_lds(
        (const __attribute__((address_space(1))) void*)g,
        (__attribute__((address_space(3))) void*)l, 16, 0, 0);
}

// ---------------------------------------------------------------------------
__global__ __launch_bounds__(256) void f2b_conv(
    const float* __restrict__ in, unsigned short* __restrict__ outb, int n4)
{
    int i = blockIdx.x * 256 + threadIdx.x;
    if (i >= n4) return;
    float4_t v = *(const float4_t*)(in + (size_t)i * 4);
    ushort4_t o;
#pragma unroll
    for (int j = 0; j < 4; j++) o[j] = f2bf(v[j]);
    *(ushort4_t*)(outb + (size_t)i * 4) = o;
}

// transpose + fp32->bf16: in [R][C] f32 -> out [C][R] bf16
__global__ __launch_bounds__(256) void transpose_f2b(
    const float* __restrict__ in, unsigned short* __restrict__ outb, int R, int C)
{
    __shared__ float tile[32][33];
    const int c0 = blockIdx.x * 32, r0 = blockIdx.y * 32;
    const int tx = threadIdx.x & 31, ty = threadIdx.x >> 5;
#pragma unroll
    for (int i = 0; i < 32; i += 8)
        tile[ty + i][tx] = in[(size_t)(r0 + ty + i) * C + c0 + tx];
    __syncthreads();
#pragma unroll
    for (int i = 0; i < 32; i += 8)
        outb[(size_t)(c0 + ty + i) * R + r0 + tx] = f2bf(tile[tx][ty + i]);
}

// u[h*768+d] = sum_e Wk[h,d,e] * bq[h,e]
__global__ __launch_bounds__(256) void wk_bq(
    const float* __restrict__ Wk, const float* __restrict__ bq, float* __restrict__ U)
{
    int i = blockIdx.x * 256 + threadIdx.x;   // 9216 total
    int h = i / 768;
    const float* wr = Wk + (size_t)i * 768;
    const float* bh = bq + (size_t)h * 768;
    float s = 0.f;
#pragma unroll 4
    for (int e = 0; e < 768; e++) s += wr[e] * bh[e];
    U[i] = s;
}

// partial[by*768+e] = sum_{r in chunk} bv[r] * Wo[r*768+e]   (96 chunks of 96)
__global__ __launch_bounds__(256) void bvwo_part(
    const float* __restrict__ Wo, const float* __restrict__ bv, float* __restrict__ part)
{
    int e = blockIdx.x * 256 + threadIdx.x;   // 768
    int r0 = blockIdx.y * 96;
    float s = 0.f;
#pragma unroll 4
    for (int r = r0; r < r0 + 96; r++) s += bv[r] * Wo[(size_t)r * 768 + e];
    part[(size_t)blockIdx.y * 768 + e] = s;
}

__global__ __launch_bounds__(256) void bvwo_final(
    const float* __restrict__ part, const float* __restrict__ bo, float* __restrict__ R)
{
    int e = blockIdx.x * 256 + threadIdx.x;   // 768
    float s = bo[e];
#pragma unroll
    for (int c = 0; c < 96; c++) s += part[(size_t)c * 768 + e];
    R[e] = s;
}

// ---------------------------------------------------------------------------
// LayerNorm over 768 cols, fp32 in -> bf16 out. One block (256 thr) per row.
// ---------------------------------------------------------------------------
__global__ __launch_bounds__(256) void layernorm768(
    const float* __restrict__ in, const float* __restrict__ g,
    const float* __restrict__ be, unsigned short* __restrict__ outb)
{
    const size_t rowoff = (size_t)blockIdx.x * 768;
    const float* xr = in + rowoff;
    const int t = threadIdx.x;
    float v0 = xr[t], v1 = xr[t + 256], v2 = xr[t + 512];
    __shared__ float red[8];
    float s = v0 + v1 + v2;
#pragma unroll
    for (int o = 32; o; o >>= 1) s += __shfl_down(s, o);
    if ((t & 63) == 0) red[t >> 6] = s;
    __syncthreads();
    float mu = (red[0] + red[1] + red[2] + red[3]) * (1.0f / 768.0f);
    float d0 = v0 - mu, d1 = v1 - mu, d2 = v2 - mu;
    float q = d0 * d0 + d1 * d1 + d2 * d2;
#pragma unroll
    for (int o = 32; o; o >>= 1) q += __shfl_down(q, o);
    if ((t & 63) == 0) red[4 + (t >> 6)] = q;
    __syncthreads();
    float rs = rsqrtf((red[4] + red[5] + red[6] + red[7]) * (1.0f / 768.0f) + 1e-5f);
    outb[rowoff + t]       = f2bf(d0 * rs * g[t]       + be[t]);
    outb[rowoff + t + 256] = f2bf(d1 * rs * g[t + 256] + be[t + 256]);
    outb[rowoff + t + 512] = f2bf(d2 * rs * g[t + 512] + be[t + 512]);
}

// ---------------------------------------------------------------------------
// In-place row softmax over contiguous 1024-wide segments, bf16.
// ---------------------------------------------------------------------------
__global__ __launch_bounds__(256) void softmax1024(unsigned short* __restrict__ p)
{
    unsigned short* row = p + (size_t)blockIdx.x * 1024;
    const int t = threadIdx.x;
    ushort4_t uv = *(const ushort4_t*)(row + t * 4);
    float v[4];
    float m = -3.4e38f;
#pragma unroll
    for (int i = 0; i < 4; i++) { v[i] = bf2f(uv[i]); m = fmaxf(m, v[i]); }
    __shared__ float red[8];
#pragma unroll
    for (int o = 32; o; o >>= 1) m = fmaxf(m, __shfl_down(m, o));
    if ((t & 63) == 0) red[t >> 6] = m;
    __syncthreads();
    m = fmaxf(fmaxf(red[0], red[1]), fmaxf(red[2], red[3]));
    float s = 0.f;
#pragma unroll
    for (int i = 0; i < 4; i++) { v[i] = __expf(v[i] - m); s += v[i]; }
#pragma unroll
    for (int o = 32; o; o >>= 1) s += __shfl_down(s, o);
    if ((t & 63) == 0) red[4 + (t >> 6)] = s;
    __syncthreads();
    float inv = 1.f / (red[4] + red[5] + red[6] + red[7]);
    ushort4_t ov;
#pragma unroll
    for (int i = 0; i < 4; i++) ov[i] = f2bf(v[i] * inv);
    *(ushort4_t*)(row + t * 4) = ov;
}

// ---------------------------------------------------------------------------
// dst[i] = res[i] + colb[i%768] + p0+p1+p2+p3   (f32, float4-vectorized)
// ---------------------------------------------------------------------------
__global__ __launch_bounds__(256) void reduce4(
    const float* __restrict__ res, const float* __restrict__ colb,
    const float* __restrict__ p0, const float* __restrict__ p1,
    const float* __restrict__ p2, const float* __restrict__ p3,
    float* __restrict__ dst)
{
    int i = blockIdx.x * 256 + threadIdx.x;         // float4 index
    float4_t r = *(const float4_t*)(res + (size_t)i * 4);
    float4_t a = *(const float4_t*)(p0 + (size_t)i * 4);
    float4_t b = *(const float4_t*)(p1 + (size_t)i * 4);
    float4_t c = *(const float4_t*)(p2 + (size_t)i * 4);
    float4_t d = *(const float4_t*)(p3 + (size_t)i * 4);
    float4_t cb = *(const float4_t*)(colb + (size_t)(i % 192) * 4);
    float4_t o;
#pragma unroll
    for (int j = 0; j < 4; j++) o[j] = r[j] + cb[j] + (a[j] + b[j]) + (c[j] + d[j]);
    *(float4_t*)(dst + (size_t)i * 4) = o;
}

enum { MODE_BF16 = 0, MODE_VT = 1, MODE_F32RES = 2 };

// ---------------------------------------------------------------------------
// gemm_bt: C[M,N] = A[M,K] * Bt[N,K]^T, bf16 in / f32 acc. 128x128 tile,
// BK=32, 4 waves. RING-4 LDS pipeline, one barrier per K-step:
//   vmcnt(8|4|0) ; s_barrier ; stage(kt+3) ; ds_read(kt) ; lgkmcnt(0) ;
//   sched_barrier(0) ; setprio(1) 16xMFMA setprio(0)
// Safety: stage(kt+3) writes buf[(kt-1)&3] -- every wave's kt-1 reads were
// lgkmcnt(0)-confirmed before the top barrier. Per-wave vmcnt precedes the
// barrier, so all waves' tile-kt DMA loads have landed once any wave passes.
// ---------------------------------------------------------------------------
template <int MODE, bool RELU>
__global__ __launch_bounds__(256) void gemm_bt(
    const unsigned short* __restrict__ A, int lda,
    const unsigned short* __restrict__ Bt, int ldb,
    void* __restrict__ Cout, int ldc,
    const float* __restrict__ bias,
    const float* __restrict__ res, int ldr,
    float scale, int K, int zdiv,
    long long sA1, long long sA2, long long sB1, long long sB2,
    long long sC1, long long sC2, long long sCJ, long long sBias)
{
    // --- m204 bijective XCD swizzle ---
    const unsigned gx = gridDim.x, gy = gridDim.y;
    const unsigned nwg = gx * gy * gridDim.z;
    unsigned lin = blockIdx.x + gx * (blockIdx.y + gy * blockIdx.z);
    {
        const unsigned q = nwg >> 3, r = nwg & 7;
        const unsigned xcd = lin & 7, idx = lin >> 3;
        lin = (xcd < r ? xcd * (q + 1) : r * (q + 1) + (xcd - r) * q) + idx;
    }
    const unsigned bx = lin % gx;
    const unsigned rem = lin / gx;
    const unsigned by = rem % gy, bz = rem / gy;

    const int z = (int)bz, zq = z / zdiv, zr = z % zdiv;
    A  += (size_t)zq * sA1 + (size_t)zr * sA2;
    Bt += (size_t)zq * sB1 + (size_t)zr * sB2;
    const size_t cOff = (size_t)zq * sC1 + (size_t)(zq >> 1) * sCJ + (size_t)zr * sC2;
    const float* biasp = bias ? bias + (size_t)zr * sBias : nullptr;

    const int m0 = by * 128, n0 = bx * 128;

    __shared__ __align__(16) unsigned short As[4][128 * 32];   // 32 KiB
    __shared__ __align__(16) unsigned short Bs[4][128 * 32];   // 32 KiB

    const int t = threadIdx.x, lane = t & 63, wave = t >> 6;
    const int wr = wave >> 1, wc = wave & 1;

    f32x4 zero = {0.f, 0.f, 0.f, 0.f};
    f32x4 acc[4][4];
#pragma unroll
    for (int i = 0; i < 4; i++)
#pragma unroll
        for (int j = 0; j < 4; j++) acc[i][j] = zero;

    const int r0 = t >> 2;              // staging row (t*16B)/64B
    const int ce = (t & 3) * 8;         // elem col within 32-elem row
    const int kq = (lane >> 4) * 8, rr = lane & 15;

    const int nt = K >> 5;              // K-tiles of 32 (>= 24 in all uses)

    auto stage = [&](int kt) {
        const int buf = kt & 3;
        const int kk = kt * 32;
        const unsigned short* ga0 = A  + (size_t)(m0 + r0) * lda      + kk + ce;
        const unsigned short* ga1 = A  + (size_t)(m0 + 64 + r0) * lda + kk + ce;
        const unsigned short* gb0 = Bt + (size_t)(n0 + r0) * ldb      + kk + ce;
        const unsigned short* gb1 = Bt + (size_t)(n0 + 64 + r0) * ldb + kk + ce;
        char* la = (char*)(&As[buf][0]);
        char* lb = (char*)(&Bs[buf][0]);
        gld16(ga0, la + wave * 1024);
        gld16(ga1, la + 4096 + wave * 1024);
        gld16(gb0, lb + wave * 1024);
        gld16(gb1, lb + 4096 + wave * 1024);
    };

    // prologue: tiles 0,1,2 in flight (12 loads/thread... 4 per tile)
    stage(0);
    stage(1);
    stage(2);

    for (int kt = 0; kt < nt; ++kt) {
        const int ahead = nt - 1 - kt;  // issued tiles beyond kt: min(ahead,2)
        if (ahead >= 2)      asm volatile("s_waitcnt vmcnt(8)" ::: "memory");
        else if (ahead == 1) asm volatile("s_waitcnt vmcnt(4)" ::: "memory");
        else                 asm volatile("s_waitcnt vmcnt(0)" ::: "memory");
        __builtin_amdgcn_s_barrier();

        if (kt + 3 < nt) stage(kt + 3);   // into buf[(kt-1)&3], dead since barrier

        bf16x8 a[4], b[4];
        const unsigned short* Ab = &As[kt & 3][0];
        const unsigned short* Bb = &Bs[kt & 3][0];
#pragma unroll
        for (int i = 0; i < 4; i++) {
            a[i] = *(const bf16x8*)(Ab + (wr * 64 + i * 16 + rr) * 32 + kq);
            b[i] = *(const bf16x8*)(Bb + (wc * 64 + i * 16 + rr) * 32 + kq);
        }
        asm volatile("s_waitcnt lgkmcnt(0)" ::: "memory");
        __builtin_amdgcn_sched_barrier(0);   // rule #18: keep MFMA below the wait

        __builtin_amdgcn_s_setprio(1);
#pragma unroll
        for (int i = 0; i < 4; i++)
#pragma unroll
            for (int j = 0; j < 4; j++)
                acc[i][j] = __builtin_amdgcn_mfma_f32_16x16x32_bf16(a[i], b[j], acc[i][j], 0, 0, 0);
        __builtin_amdgcn_s_setprio(0);
    }

    // epilogue; C/D frag: col = lane&15, row = 4*(lane>>4) + reg   [m89]
    const int cr = (lane >> 4) * 4, cc = lane & 15;
#pragma unroll
    for (int i = 0; i < 4; i++) {
        const int rowb = m0 + wr * 64 + i * 16 + cr;
#pragma unroll
        for (int j = 0; j < 4; j++) {
            const int col = n0 + wc * 64 + j * 16 + cc;
            const float bv = biasp ? biasp[col] : 0.f;
            if (MODE == MODE_VT) {
                ushort4_t pk;
#pragma unroll
                for (int r = 0; r < 4; r++) {
                    float v = acc[i][j][r] * scale + bv;
                    if (RELU) v = fmaxf(v, 0.f);
                    pk[r] = f2bf(v);
                }
                *(ushort4_t*)((unsigned short*)Cout + cOff +
                              (size_t)col * ldc + rowb) = pk;
            } else {
#pragma unroll
                for (int r = 0; r < 4; r++) {
                    float v = acc[i][j][r] * scale + bv;
                    if (RELU) v = fmaxf(v, 0.f);
                    const int row = rowb + r;
                    if (MODE == MODE_BF16) {
                        ((unsigned short*)Cout)[cOff + (size_t)row * ldc + col] = f2bf(v);
                    } else {
                        float ov = res ? v + res[(size_t)row * ldr + col] : v;
                        ((float*)Cout)[cOff + (size_t)row * ldc + col] = ov;
                    }
                }
            }
        }
    }
}

__global__ void ws_too_small(float* o, float v) { o[0] = v; }

// ---------------------------------------------------------------------------
extern "C" void kernel_launch(void* const* d_in, const int* in_sizes, int n_in,
                              void* d_out, int out_size, void* d_ws, size_t ws_size,
                              hipStream_t stream)
{
    const float* x   = (const float*)d_in[0];
    const float* Wq  = (const float*)d_in[1];
    const float* bq  = (const float*)d_in[2];
    const float* Wk  = (const float*)d_in[3];
    const float* Wv  = (const float*)d_in[5];
    const float* bv  = (const float*)d_in[6];
    const float* Wo  = (const float*)d_in[7];
    const float* bo  = (const float*)d_in[8];
    const float* W1  = (const float*)d_in[9];
    const float* b1  = (const float*)d_in[10];
    const float* W2  = (const float*)d_in[11];
    const float* b2  = (const float*)d_in[12];
    const float* g1  = (const float*)d_in[13];
    const float* be1 = (const float*)d_in[14];
    const float* g2  = (const float*)d_in[15];
    const float* be2 = (const float*)d_in[16];
    float* out = (float*)d_out;

    // --- workspace layout (peak 258,284,544 B < 256 MiB) ---
    char* ws = (char*)d_ws;
    unsigned short* W1T  = (unsigned short*)(ws);             // [3072][768]
    unsigned short* W2T  = (unsigned short*)(ws + 4718592);   // [768][3072]
    unsigned short* WQKT = (unsigned short*)(ws + 9437184);   // [12][768(d')][768(d)]
    unsigned short* WVOT = (unsigned short*)(ws + 23592960);  // [12][768(e)][768(d)]
    float*          U    = (float*)(ws + 37748736);           // [12][768]
    float*          BVWO = (float*)(ws + 37785600);           // [768]
    float*          PART = (float*)(ws + 37788672);           // [96][768]
    unsigned short* HB   = (unsigned short*)(ws + 38083584);  // [4096][768] LN1
    float*          X1   = (float*)(ws + 44375040);           // [4096][768] f32
    unsigned short* TB   = (unsigned short*)(ws + 56957952);  // [4][12][1024][768]
    unsigned short* SC   = (unsigned short*)(ws + 132455424); // [4096][12288]
    const size_t NEED = 258284544;

    if (ws_size < NEED) {   // diagnostic: absmax in the log equals ws_size
        hipMemsetAsync(d_out, 0, (size_t)out_size * sizeof(float), stream);
        ws_too_small<<<1, 1, 0, stream>>>(out, (float)ws_size);
        return;
    }

    // overlays (time-disjoint):
    unsigned short* VOT = TB;                                  // [4][768][12288] after softmax
    // split-K f32 partials [4096][768] x4: over dead WQKT/WVOT + tail
    float* P0 = (float*)(ws + 9437184);
    float* P1 = (float*)(ws + 22020096);
    float* P2 = (float*)(ws + 233118720);
    float* P3 = (float*)(ws + 245701632);
    // cOff: c*3145728 + (c>>1)*49628928 floats from P0 base
    unsigned short* WqB = (unsigned short*)(ws + 132455424);   // prep over not-yet-live SC
    unsigned short* WkB = (unsigned short*)(ws + 146611200);
    unsigned short* WvB = (unsigned short*)(ws + 160766976);
    unsigned short* WOT = (unsigned short*)(ws + 174922752);   // [768][9216]
    unsigned short* H2B = (unsigned short*)(ws + 56957952);    // post-attn over TB/VOT
    unsigned short* FFN = (unsigned short*)(ws + 63249408);    // [4096][3072]

    // ---- weight preparation ----
    f2b_conv<<<6912, 256, 0, stream>>>(Wq, WqB, 1769472);
    f2b_conv<<<6912, 256, 0, stream>>>(Wk, WkB, 1769472);
    f2b_conv<<<6912, 256, 0, stream>>>(Wv, WvB, 1769472);
    transpose_f2b<<<dim3(24, 288), 256, 0, stream>>>(Wo, WOT, 9216, 768);
    transpose_f2b<<<dim3(96, 24), 256, 0, stream>>>(W1, W1T, 768, 3072);
    transpose_f2b<<<dim3(24, 96), 256, 0, stream>>>(W2, W2T, 3072, 768);

    // WQKT[h][d'][d] = sum_m Wk[h,d',m] Wq[h,d,m]
    gemm_bt<MODE_BF16, false><<<dim3(6, 6, 12), 256, 0, stream>>>(
        WkB, 768, WqB, 768, WQKT, 768, nullptr, nullptr, 0, 1.0f, 768, 12,
        0, 589824, 0, 589824, 0, 589824, 0, 0);
    // WVOT[h][e][d] = sum_m Wo[h*768+m,e] Wv[h,d,m]
    gemm_bt<MODE_BF16, false><<<dim3(6, 6, 12), 256, 0, stream>>>(
        WOT, 9216, WvB, 768, WVOT, 768, nullptr, nullptr, 0, 1.0f, 768, 12,
        0, 768, 0, 589824, 0, 589824, 0, 0);

    wk_bq<<<36, 256, 0, stream>>>(Wk, bq, U);
    bvwo_part<<<dim3(3, 96), 256, 0, stream>>>(Wo, bv, PART);
    bvwo_final<<<3, 256, 0, stream>>>(PART, bo, BVWO);

    layernorm768<<<4096, 256, 0, stream>>>(x, g1, be1, HB);

    // T[b][h][s][d'] = LN1_b @ Wqk_h + u_h        (zq=b, zr=h)
    gemm_bt<MODE_BF16, false><<<dim3(6, 8, 48), 256, 0, stream>>>(
        HB, 768, WQKT, 768, TB, 768, U, nullptr, 0, 1.0f, 768, 12,
        786432, 0, 0, 589824, 9437184, 786432, 0, 768);

    // scores[b*1024+s][h*1024+t] = scale * T_bh @ LN1_b^T
    gemm_bt<MODE_BF16, false><<<dim3(8, 8, 48), 256, 0, stream>>>(
        TB, 768, HB, 768, SC, 12288, nullptr, nullptr, 0,
        0.03608439182435161f, 768, 12,
        9437184, 786432, 786432, 0, 12582912, 1024, 0, 0);

    softmax1024<<<49152, 256, 0, stream>>>(SC);

    // VOT[b][e][h*1024+t] = (LN1_b @ Wvo_h)^T     (transposed store; over TB)
    gemm_bt<MODE_VT, false><<<dim3(6, 8, 48), 256, 0, stream>>>(
        HB, 768, WVOT, 768, VOT, 12288, nullptr, nullptr, 0, 1.0f, 768, 12,
        786432, 0, 0, 589824, 9437184, 1024, 0, 0);

    // PV split-K 4: P{c}[b*1024+s][e] = P_chunk @ VO_chunk  (zq=c, zr=b)
    gemm_bt<MODE_F32RES, false><<<dim3(6, 8, 16), 256, 0, stream>>>(
        SC, 12288, VOT, 12288, P0, 768, nullptr, nullptr, 0, 1.0f, 3072, 4,
        3072, 12582912, 3072, 9437184, 3145728, 786432, 49628928, 0);

    // x1 = x + BVWO + P0..P3
    reduce4<<<3072, 256, 0, stream>>>(x, BVWO, P0, P1, P2, P3, X1);

    layernorm768<<<4096, 256, 0, stream>>>(X1, g2, be2, H2B);

    // ffn1 = relu(h2 @ W1 + b1)
    gemm_bt<MODE_BF16, true><<<dim3(24, 32, 1), 256, 0, stream>>>(
        H2B, 768, W1T, 768, FFN, 3072, b1, nullptr, 0, 1.0f, 768, 1,
        0, 0, 0, 0, 0, 0, 0, 0);

    // FFN2 split-K 4: Q{c} = ffn1_chunk @ W2_chunk   (zq=c)
    gemm_bt<MODE_F32RES, false><<<dim3(6, 32, 4), 256, 0, stream>>>(
        FFN, 3072, W2T, 3072, P0, 768, nullptr, nullptr, 0, 1.0f, 768, 1,
        768, 0, 768, 0, 3145728, 0, 49628928, 0);

    // out = x1 + b2 + Q0..Q3
    reduce4<<<3072, 256, 0, stream>>>(X1, b2, P0, P1, P2, P3, out);
}

// Round 13
// 656.840 us; speedup vs baseline: 1.2189x; 1.2189x over previous
//
#include <hip/hip_runtime.h>
#include <hip/hip_bf16.h>

// ---------------------------------------------------------------------------
// Transformer block, algebraically folded:
//   Wqk_h = Wq_h Wk_h^T   -> scores = scale*(LN1 Wqk_h + 1*(Wk_h bq_h)^T) LN1^T
//   Wvo_h = Wv_h Wo_h     -> x1 = x + sum_h P_h (LN1 Wvo_h) + (bo + sum_h bv_h Wo_h)
// P stored [s][h*1024+t], VO stored [e][h*1024+t] -> sum_h P_h VO_h is ONE
// GEMM with K=12288, split-K 4 into f32 partials + fused reduce.
//
// GEMM core: R8-proven 128x128 tile, BK=32, 2-buffer LDS (32 KiB -> ~5
// blocks/CU TLP), 2-phase counted-vmcnt pipeline, m204 XCD swizzle.
// This round: restore R8 verbatim + fuse (reduce4+LN2) and (3x f2b_conv).
// ---------------------------------------------------------------------------

typedef __attribute__((ext_vector_type(8))) __bf16 bf16x8;
typedef __attribute__((ext_vector_type(4))) float f32x4;
typedef __attribute__((ext_vector_type(4))) float float4_t;
typedef __attribute__((ext_vector_type(4))) unsigned short ushort4_t;

#define DEV __device__ __forceinline__

DEV unsigned short f2bf(float f) {
    __hip_bfloat16 h = __float2bfloat16(f);
    return *reinterpret_cast<unsigned short*>(&h);
}
DEV float bf2f(unsigned short u) {
    return __uint_as_float(((unsigned int)u) << 16);
}

DEV void gld16(const void* g, void* l) {
    __builtin_amdgcn_global_load_lds(
        (const __attribute__((address_space(1))) void*)g,
        (__attribute__((address_space(3))) void*)l, 16, 0, 0);
}

// ---------------------------------------------------------------------------
// z-batched fp32 -> bf16 convert of 3 equal-size weight tensors
// ---------------------------------------------------------------------------
__global__ __launch_bounds__(256) void f2b_conv3(
    const float* __restrict__ in0, const float* __restrict__ in1,
    const float* __restrict__ in2,
    unsigned short* __restrict__ o0, unsigned short* __restrict__ o1,
    unsigned short* __restrict__ o2, int n4)
{
    int i = blockIdx.x * 256 + threadIdx.x;
    if (i >= n4) return;
    const float* in = blockIdx.y == 0 ? in0 : (blockIdx.y == 1 ? in1 : in2);
    unsigned short* ob = blockIdx.y == 0 ? o0 : (blockIdx.y == 1 ? o1 : o2);
    float4_t v = *(const float4_t*)(in + (size_t)i * 4);
    ushort4_t o;
#pragma unroll
    for (int j = 0; j < 4; j++) o[j] = f2bf(v[j]);
    *(ushort4_t*)(ob + (size_t)i * 4) = o;
}

// transpose + fp32->bf16: in [R][C] f32 -> out [C][R] bf16
__global__ __launch_bounds__(256) void transpose_f2b(
    const float* __restrict__ in, unsigned short* __restrict__ outb, int R, int C)
{
    __shared__ float tile[32][33];
    const int c0 = blockIdx.x * 32, r0 = blockIdx.y * 32;
    const int tx = threadIdx.x & 31, ty = threadIdx.x >> 5;
#pragma unroll
    for (int i = 0; i < 32; i += 8)
        tile[ty + i][tx] = in[(size_t)(r0 + ty + i) * C + c0 + tx];
    __syncthreads();
#pragma unroll
    for (int i = 0; i < 32; i += 8)
        outb[(size_t)(c0 + ty + i) * R + r0 + tx] = f2bf(tile[tx][ty + i]);
}

// u[h*768+d] = sum_e Wk[h,d,e] * bq[h,e]
__global__ __launch_bounds__(256) void wk_bq(
    const float* __restrict__ Wk, const float* __restrict__ bq, float* __restrict__ U)
{
    int i = blockIdx.x * 256 + threadIdx.x;   // 9216 total
    int h = i / 768;
    const float* wr = Wk + (size_t)i * 768;
    const float* bh = bq + (size_t)h * 768;
    float s = 0.f;
#pragma unroll 4
    for (int e = 0; e < 768; e++) s += wr[e] * bh[e];
    U[i] = s;
}

// partial[by*768+e] = sum_{r in chunk} bv[r] * Wo[r*768+e]   (96 chunks of 96)
__global__ __launch_bounds__(256) void bvwo_part(
    const float* __restrict__ Wo, const float* __restrict__ bv, float* __restrict__ part)
{
    int e = blockIdx.x * 256 + threadIdx.x;   // 768
    int r0 = blockIdx.y * 96;
    float s = 0.f;
#pragma unroll 4
    for (int r = r0; r < r0 + 96; r++) s += bv[r] * Wo[(size_t)r * 768 + e];
    part[(size_t)blockIdx.y * 768 + e] = s;
}

__global__ __launch_bounds__(256) void bvwo_final(
    const float* __restrict__ part, const float* __restrict__ bo, float* __restrict__ R)
{
    int e = blockIdx.x * 256 + threadIdx.x;   // 768
    float s = bo[e];
#pragma unroll
    for (int c = 0; c < 96; c++) s += part[(size_t)c * 768 + e];
    R[e] = s;
}

// ---------------------------------------------------------------------------
// LayerNorm over 768 cols, fp32 in -> bf16 out. One block (256 thr) per row.
// ---------------------------------------------------------------------------
__global__ __launch_bounds__(256) void layernorm768(
    const float* __restrict__ in, const float* __restrict__ g,
    const float* __restrict__ be, unsigned short* __restrict__ outb)
{
    const size_t rowoff = (size_t)blockIdx.x * 768;
    const float* xr = in + rowoff;
    const int t = threadIdx.x;
    float v0 = xr[t], v1 = xr[t + 256], v2 = xr[t + 512];
    __shared__ float red[8];
    float s = v0 + v1 + v2;
#pragma unroll
    for (int o = 32; o; o >>= 1) s += __shfl_down(s, o);
    if ((t & 63) == 0) red[t >> 6] = s;
    __syncthreads();
    float mu = (red[0] + red[1] + red[2] + red[3]) * (1.0f / 768.0f);
    float d0 = v0 - mu, d1 = v1 - mu, d2 = v2 - mu;
    float q = d0 * d0 + d1 * d1 + d2 * d2;
#pragma unroll
    for (int o = 32; o; o >>= 1) q += __shfl_down(q, o);
    if ((t & 63) == 0) red[4 + (t >> 6)] = q;
    __syncthreads();
    float rs = rsqrtf((red[4] + red[5] + red[6] + red[7]) * (1.0f / 768.0f) + 1e-5f);
    outb[rowoff + t]       = f2bf(d0 * rs * g[t]       + be[t]);
    outb[rowoff + t + 256] = f2bf(d1 * rs * g[t + 256] + be[t + 256]);
    outb[rowoff + t + 512] = f2bf(d2 * rs * g[t + 512] + be[t + 512]);
}

// ---------------------------------------------------------------------------
// Fused: x1 = res + colb + p0+p1+p2+p3 (write f32) THEN LayerNorm(x1) -> bf16.
// One block (256 thr) per row of 768.
// ---------------------------------------------------------------------------
__global__ __launch_bounds__(256) void reduce4_ln(
    const float* __restrict__ res, const float* __restrict__ colb,
    const float* __restrict__ p0, const float* __restrict__ p1,
    const float* __restrict__ p2, const float* __restrict__ p3,
    const float* __restrict__ g, const float* __restrict__ be,
    float* __restrict__ x1out, unsigned short* __restrict__ outb)
{
    const size_t rowoff = (size_t)blockIdx.x * 768;
    const int t = threadIdx.x;
    float v[3];
#pragma unroll
    for (int j = 0; j < 3; j++) {
        const size_t i = rowoff + t + j * 256;
        const int e = t + j * 256;
        v[j] = res[i] + colb[e] + (p0[i] + p1[i]) + (p2[i] + p3[i]);
        x1out[i] = v[j];
    }
    __shared__ float red[8];
    float s = v[0] + v[1] + v[2];
#pragma unroll
    for (int o = 32; o; o >>= 1) s += __shfl_down(s, o);
    if ((t & 63) == 0) red[t >> 6] = s;
    __syncthreads();
    float mu = (red[0] + red[1] + red[2] + red[3]) * (1.0f / 768.0f);
    float d0 = v[0] - mu, d1 = v[1] - mu, d2 = v[2] - mu;
    float q = d0 * d0 + d1 * d1 + d2 * d2;
#pragma unroll
    for (int o = 32; o; o >>= 1) q += __shfl_down(q, o);
    if ((t & 63) == 0) red[4 + (t >> 6)] = q;
    __syncthreads();
    float rs = rsqrtf((red[4] + red[5] + red[6] + red[7]) * (1.0f / 768.0f) + 1e-5f);
    outb[rowoff + t]       = f2bf(d0 * rs * g[t]       + be[t]);
    outb[rowoff + t + 256] = f2bf(d1 * rs * g[t + 256] + be[t + 256]);
    outb[rowoff + t + 512] = f2bf(d2 * rs * g[t + 512] + be[t + 512]);
}

// ---------------------------------------------------------------------------
// In-place row softmax over contiguous 1024-wide segments, bf16.
// ---------------------------------------------------------------------------
__global__ __launch_bounds__(256) void softmax1024(unsigned short* __restrict__ p)
{
    unsigned short* row = p + (size_t)blockIdx.x * 1024;
    const int t = threadIdx.x;
    ushort4_t uv = *(const ushort4_t*)(row + t * 4);
    float v[4];
    float m = -3.4e38f;
#pragma unroll
    for (int i = 0; i < 4; i++) { v[i] = bf2f(uv[i]); m = fmaxf(m, v[i]); }
    __shared__ float red[8];
#pragma unroll
    for (int o = 32; o; o >>= 1) m = fmaxf(m, __shfl_down(m, o));
    if ((t & 63) == 0) red[t >> 6] = m;
    __syncthreads();
    m = fmaxf(fmaxf(red[0], red[1]), fmaxf(red[2], red[3]));
    float s = 0.f;
#pragma unroll
    for (int i = 0; i < 4; i++) { v[i] = __expf(v[i] - m); s += v[i]; }
#pragma unroll
    for (int o = 32; o; o >>= 1) s += __shfl_down(s, o);
    if ((t & 63) == 0) red[4 + (t >> 6)] = s;
    __syncthreads();
    float inv = 1.f / (red[4] + red[5] + red[6] + red[7]);
    ushort4_t ov;
#pragma unroll
    for (int i = 0; i < 4; i++) ov[i] = f2bf(v[i] * inv);
    *(ushort4_t*)(row + t * 4) = ov;
}

// ---------------------------------------------------------------------------
// dst[i] = res[i] + colb[i%768] + p0+p1+p2+p3   (f32, float4-vectorized)
// ---------------------------------------------------------------------------
__global__ __launch_bounds__(256) void reduce4(
    const float* __restrict__ res, const float* __restrict__ colb,
    const float* __restrict__ p0, const float* __restrict__ p1,
    const float* __restrict__ p2, const float* __restrict__ p3,
    float* __restrict__ dst)
{
    int i = blockIdx.x * 256 + threadIdx.x;         // float4 index
    float4_t r = *(const float4_t*)(res + (size_t)i * 4);
    float4_t a = *(const float4_t*)(p0 + (size_t)i * 4);
    float4_t b = *(const float4_t*)(p1 + (size_t)i * 4);
    float4_t c = *(const float4_t*)(p2 + (size_t)i * 4);
    float4_t d = *(const float4_t*)(p3 + (size_t)i * 4);
    float4_t cb = *(const float4_t*)(colb + (size_t)(i % 192) * 4);
    float4_t o;
#pragma unroll
    for (int j = 0; j < 4; j++) o[j] = r[j] + cb[j] + (a[j] + b[j]) + (c[j] + d[j]);
    *(float4_t*)(dst + (size_t)i * 4) = o;
}

enum { MODE_BF16 = 0, MODE_VT = 1, MODE_F32RES = 2 };

// ---------------------------------------------------------------------------
// gemm_bt (R8-proven): C[M,N] = A[M,K] * Bt[N,K]^T, bf16 in / f32 acc.
// 128x128 tile, BK=32, 4 waves, 2-buffer LDS (32 KiB), 2-phase pipeline
// with counted vmcnt(4), m204 XCD-bijective block swizzle.
// ---------------------------------------------------------------------------
template <int MODE, bool RELU>
__global__ __launch_bounds__(256) void gemm_bt(
    const unsigned short* __restrict__ A, int lda,
    const unsigned short* __restrict__ Bt, int ldb,
    void* __restrict__ Cout, int ldc,
    const float* __restrict__ bias,
    const float* __restrict__ res, int ldr,
    float scale, int K, int zdiv,
    long long sA1, long long sA2, long long sB1, long long sB2,
    long long sC1, long long sC2, long long sCJ, long long sBias)
{
    const unsigned gx = gridDim.x, gy = gridDim.y;
    const unsigned nwg = gx * gy * gridDim.z;
    unsigned lin = blockIdx.x + gx * (blockIdx.y + gy * blockIdx.z);
    {
        const unsigned q = nwg >> 3, r = nwg & 7;
        const unsigned xcd = lin & 7, idx = lin >> 3;
        lin = (xcd < r ? xcd * (q + 1) : r * (q + 1) + (xcd - r) * q) + idx;
    }
    const unsigned bx = lin % gx;
    const unsigned rem = lin / gx;
    const unsigned by = rem % gy, bz = rem / gy;

    const int z = (int)bz, zq = z / zdiv, zr = z % zdiv;
    A  += (size_t)zq * sA1 + (size_t)zr * sA2;
    Bt += (size_t)zq * sB1 + (size_t)zr * sB2;
    const size_t cOff = (size_t)zq * sC1 + (size_t)(zq >> 1) * sCJ + (size_t)zr * sC2;
    const float* biasp = bias ? bias + (size_t)zr * sBias : nullptr;

    const int m0 = by * 128, n0 = bx * 128;

    __shared__ __align__(16) unsigned short As[2][128 * 32];
    __shared__ __align__(16) unsigned short Bs[2][128 * 32];

    const int t = threadIdx.x, lane = t & 63, wave = t >> 6;
    const int wr = wave >> 1, wc = wave & 1;

    f32x4 zero = {0.f, 0.f, 0.f, 0.f};
    f32x4 acc[4][4];
#pragma unroll
    for (int i = 0; i < 4; i++)
#pragma unroll
        for (int j = 0; j < 4; j++) acc[i][j] = zero;

    const int r0 = t >> 2;              // staging row (t*16B)/64B
    const int ce = (t & 3) * 8;         // elem col within 32-elem row
    const int kq = (lane >> 4) * 8, rr = lane & 15;

    const int nt = K >> 5;              // K-tiles of 32 (always >= 2 here)

    auto stage = [&](int buf, int kt) {
        const int kk = kt * 32;
        const unsigned short* ga0 = A  + (size_t)(m0 + r0) * lda      + kk + ce;
        const unsigned short* ga1 = A  + (size_t)(m0 + 64 + r0) * lda + kk + ce;
        const unsigned short* gb0 = Bt + (size_t)(n0 + r0) * ldb      + kk + ce;
        const unsigned short* gb1 = Bt + (size_t)(n0 + 64 + r0) * ldb + kk + ce;
        char* la = (char*)(&As[buf][0]);
        char* lb = (char*)(&Bs[buf][0]);
        gld16(ga0, la + wave * 1024);
        gld16(ga1, la + 4096 + wave * 1024);
        gld16(gb0, lb + wave * 1024);
        gld16(gb1, lb + 4096 + wave * 1024);
    };

    stage(0, 0);
    stage(1, 1);
    asm volatile("s_waitcnt vmcnt(4)" ::: "memory");
    __builtin_amdgcn_s_barrier();

    int cur = 0;
    for (int kt = 0; kt < nt; ++kt) {
        bf16x8 a[4], b[4];
        const unsigned short* Ab = &As[cur][0];
        const unsigned short* Bb = &Bs[cur][0];
#pragma unroll
        for (int i = 0; i < 4; i++) {
            a[i] = *(const bf16x8*)(Ab + (wr * 64 + i * 16 + rr) * 32 + kq);
            b[i] = *(const bf16x8*)(Bb + (wc * 64 + i * 16 + rr) * 32 + kq);
        }
        asm volatile("s_waitcnt lgkmcnt(0)" ::: "memory");
        __builtin_amdgcn_s_barrier();
        if (kt + 2 < nt) stage(cur, kt + 2);

        __builtin_amdgcn_s_setprio(1);
#pragma unroll
        for (int i = 0; i < 4; i++)
#pragma unroll
            for (int j = 0; j < 4; j++)
                acc[i][j] = __builtin_amdgcn_mfma_f32_16x16x32_bf16(a[i], b[j], acc[i][j], 0, 0, 0);
        __builtin_amdgcn_s_setprio(0);

        if (kt + 2 < nt) asm volatile("s_waitcnt vmcnt(4)" ::: "memory");
        else             asm volatile("s_waitcnt vmcnt(0)" ::: "memory");
        __builtin_amdgcn_s_barrier();
        cur ^= 1;
    }

    // epilogue; C/D frag: col = lane&15, row = 4*(lane>>4) + reg   [m89]
    const int cr = (lane >> 4) * 4, cc = lane & 15;
#pragma unroll
    for (int i = 0; i < 4; i++) {
        const int rowb = m0 + wr * 64 + i * 16 + cr;
#pragma unroll
        for (int j = 0; j < 4; j++) {
            const int col = n0 + wc * 64 + j * 16 + cc;
            const float bv = biasp ? biasp[col] : 0.f;
            if (MODE == MODE_VT) {
                ushort4_t pk;
#pragma unroll
                for (int r = 0; r < 4; r++) {
                    float v = acc[i][j][r] * scale + bv;
                    if (RELU) v = fmaxf(v, 0.f);
                    pk[r] = f2bf(v);
                }
                *(ushort4_t*)((unsigned short*)Cout + cOff +
                              (size_t)col * ldc + rowb) = pk;
            } else {
#pragma unroll
                for (int r = 0; r < 4; r++) {
                    float v = acc[i][j][r] * scale + bv;
                    if (RELU) v = fmaxf(v, 0.f);
                    const int row = rowb + r;
                    if (MODE == MODE_BF16) {
                        ((unsigned short*)Cout)[cOff + (size_t)row * ldc + col] = f2bf(v);
                    } else {
                        float ov = res ? v + res[(size_t)row * ldr + col] : v;
                        ((float*)Cout)[cOff + (size_t)row * ldc + col] = ov;
                    }
                }
            }
        }
    }
}

__global__ void ws_too_small(float* o, float v) { o[0] = v; }

// ---------------------------------------------------------------------------
extern "C" void kernel_launch(void* const* d_in, const int* in_sizes, int n_in,
                              void* d_out, int out_size, void* d_ws, size_t ws_size,
                              hipStream_t stream)
{
    const float* x   = (const float*)d_in[0];
    const float* Wq  = (const float*)d_in[1];
    const float* bq  = (const float*)d_in[2];
    const float* Wk  = (const float*)d_in[3];
    const float* Wv  = (const float*)d_in[5];
    const float* bv  = (const float*)d_in[6];
    const float* Wo  = (const float*)d_in[7];
    const float* bo  = (const float*)d_in[8];
    const float* W1  = (const float*)d_in[9];
    const float* b1  = (const float*)d_in[10];
    const float* W2  = (const float*)d_in[11];
    const float* b2  = (const float*)d_in[12];
    const float* g1  = (const float*)d_in[13];
    const float* be1 = (const float*)d_in[14];
    const float* g2  = (const float*)d_in[15];
    const float* be2 = (const float*)d_in[16];
    float* out = (float*)d_out;

    // --- workspace layout (peak 258,284,544 B < 256 MiB) ---
    char* ws = (char*)d_ws;
    unsigned short* W1T  = (unsigned short*)(ws);             // [3072][768]
    unsigned short* W2T  = (unsigned short*)(ws + 4718592);   // [768][3072]
    unsigned short* WQKT = (unsigned short*)(ws + 9437184);   // [12][768(d')][768(d)]
    unsigned short* WVOT = (unsigned short*)(ws + 23592960);  // [12][768(e)][768(d)]
    float*          U    = (float*)(ws + 37748736);           // [12][768]
    float*          BVWO = (float*)(ws + 37785600);           // [768]
    float*          PART = (float*)(ws + 37788672);           // [96][768]
    unsigned short* HB   = (unsigned short*)(ws + 38083584);  // [4096][768] LN1
    float*          X1   = (float*)(ws + 44375040);           // [4096][768] f32
    unsigned short* TB   = (unsigned short*)(ws + 56957952);  // [4][12][1024][768]
    unsigned short* SC   = (unsigned short*)(ws + 132455424); // [4096][12288]
    const size_t NEED = 258284544;

    if (ws_size < NEED) {   // diagnostic: absmax in the log equals ws_size
        hipMemsetAsync(d_out, 0, (size_t)out_size * sizeof(float), stream);
        ws_too_small<<<1, 1, 0, stream>>>(out, (float)ws_size);
        return;
    }

    // overlays (time-disjoint):
    unsigned short* VOT = TB;                                  // [4][768][12288] after softmax
    // split-K f32 partials [4096][768] x4: over dead WQKT/WVOT + tail
    float* P0 = (float*)(ws + 9437184);
    float* P1 = (float*)(ws + 22020096);
    float* P2 = (float*)(ws + 233118720);
    float* P3 = (float*)(ws + 245701632);
    // cOff: c*3145728 + (c>>1)*49628928 floats from P0 base
    unsigned short* WqB = (unsigned short*)(ws + 132455424);   // prep over not-yet-live SC
    unsigned short* WkB = (unsigned short*)(ws + 146611200);
    unsigned short* WvB = (unsigned short*)(ws + 160766976);
    unsigned short* WOT = (unsigned short*)(ws + 174922752);   // [768][9216]
    unsigned short* H2B = (unsigned short*)(ws + 56957952);    // post-attn over TB/VOT
    unsigned short* FFN = (unsigned short*)(ws + 63249408);    // [4096][3072]

    // ---- weight preparation ----
    f2b_conv3<<<dim3(6912, 3), 256, 0, stream>>>(Wq, Wk, Wv, WqB, WkB, WvB, 1769472);
    transpose_f2b<<<dim3(24, 288), 256, 0, stream>>>(Wo, WOT, 9216, 768);
    transpose_f2b<<<dim3(96, 24), 256, 0, stream>>>(W1, W1T, 768, 3072);
    transpose_f2b<<<dim3(24, 96), 256, 0, stream>>>(W2, W2T, 3072, 768);

    // WQKT[h][d'][d] = sum_m Wk[h,d',m] Wq[h,d,m]
    gemm_bt<MODE_BF16, false><<<dim3(6, 6, 12), 256, 0, stream>>>(
        WkB, 768, WqB, 768, WQKT, 768, nullptr, nullptr, 0, 1.0f, 768, 12,
        0, 589824, 0, 589824, 0, 589824, 0, 0);
    // WVOT[h][e][d] = sum_m Wo[h*768+m,e] Wv[h,d,m]
    gemm_bt<MODE_BF16, false><<<dim3(6, 6, 12), 256, 0, stream>>>(
        WOT, 9216, WvB, 768, WVOT, 768, nullptr, nullptr, 0, 1.0f, 768, 12,
        0, 768, 0, 589824, 0, 589824, 0, 0);

    wk_bq<<<36, 256, 0, stream>>>(Wk, bq, U);
    bvwo_part<<<dim3(3, 96), 256, 0, stream>>>(Wo, bv, PART);
    bvwo_final<<<3, 256, 0, stream>>>(PART, bo, BVWO);

    layernorm768<<<4096, 256, 0, stream>>>(x, g1, be1, HB);

    // T[b][h][s][d'] = LN1_b @ Wqk_h + u_h        (zq=b, zr=h)
    gemm_bt<MODE_BF16, false><<<dim3(6, 8, 48), 256, 0, stream>>>(
        HB, 768, WQKT, 768, TB, 768, U, nullptr, 0, 1.0f, 768, 12,
        786432, 0, 0, 589824, 9437184, 786432, 0, 768);

    // scores[b*1024+s][h*1024+t] = scale * T_bh @ LN1_b^T
    gemm_bt<MODE_BF16, false><<<dim3(8, 8, 48), 256, 0, stream>>>(
        TB, 768, HB, 768, SC, 12288, nullptr, nullptr, 0,
        0.03608439182435161f, 768, 12,
        9437184, 786432, 786432, 0, 12582912, 1024, 0, 0);

    softmax1024<<<49152, 256, 0, stream>>>(SC);

    // VOT[b][e][h*1024+t] = (LN1_b @ Wvo_h)^T     (transposed store; over TB)
    gemm_bt<MODE_VT, false><<<dim3(6, 8, 48), 256, 0, stream>>>(
        HB, 768, WVOT, 768, VOT, 12288, nullptr, nullptr, 0, 1.0f, 768, 12,
        786432, 0, 0, 589824, 9437184, 1024, 0, 0);

    // PV split-K 4: P{c}[b*1024+s][e] = P_chunk @ VO_chunk  (zq=c, zr=b)
    gemm_bt<MODE_F32RES, false><<<dim3(6, 8, 16), 256, 0, stream>>>(
        SC, 12288, VOT, 12288, P0, 768, nullptr, nullptr, 0, 1.0f, 3072, 4,
        3072, 12582912, 3072, 9437184, 3145728, 786432, 49628928, 0);

    // x1 = x + BVWO + P0..P3 ; H2 = LN2(x1)   (fused)
    reduce4_ln<<<4096, 256, 0, stream>>>(x, BVWO, P0, P1, P2, P3, g2, be2, X1, H2B);

    // ffn1 = relu(h2 @ W1 + b1)
    gemm_bt<MODE_BF16, true><<<dim3(24, 32, 1), 256, 0, stream>>>(
        H2B, 768, W1T, 768, FFN, 3072, b1, nullptr, 0, 1.0f, 768, 1,
        0, 0, 0, 0, 0, 0, 0, 0);

    // FFN2 split-K 4: Q{c} = ffn1_chunk @ W2_chunk   (zq=c)
    gemm_bt<MODE_F32RES, false><<<dim3(6, 32, 4), 256, 0, stream>>>(
        FFN, 3072, W2T, 3072, P0, 768, nullptr, nullptr, 0, 1.0f, 768, 1,
        768, 0, 768, 0, 3145728, 0, 49628928, 0);

    // out = x1 + b2 + Q0..Q3
    reduce4<<<3072, 256, 0, stream>>>(X1, b2, P0, P1, P2, P3, out);
}

// Round 14
// 635.650 us; speedup vs baseline: 1.2596x; 1.0333x over previous
//
#include <hip/hip_runtime.h>
#include <hip/hip_bf16.h>

// ---------------------------------------------------------------------------
// Transformer block, algebraically folded:
//   Wqk_h = Wq_h Wk_h^T   -> scores = scale*(LN1 Wqk_h + 1*(Wk_h bq_h)^T) LN1^T
//   Wvo_h = Wv_h Wo_h     -> x1 = x + sum_h P_h (LN1 Wvo_h) + (bo + sum_h bv_h Wo_h)
// P stored [s][h*1024+t], VO stored [e][h*1024+t] -> sum_h P_h VO_h is ONE
// GEMM with K=12288, split-K 4 into f32 partials + fused reduce+LN2.
//
// GEMM core: R8-proven 128x128 tile, BK=32, 2-buffer LDS (32 KiB), 2-phase
// counted-vmcnt pipeline, m204 XCD swizzle. This round: wave-local softmax
// (12 segs/block, no __syncthreads) + merged prep launches.
// ---------------------------------------------------------------------------

typedef __attribute__((ext_vector_type(8))) __bf16 bf16x8;
typedef __attribute__((ext_vector_type(4))) float f32x4;
typedef __attribute__((ext_vector_type(4))) float float4_t;
typedef __attribute__((ext_vector_type(4))) unsigned short ushort4_t;
typedef __attribute__((ext_vector_type(8))) unsigned short ushort8_t;

#define DEV __device__ __forceinline__

DEV unsigned short f2bf(float f) {
    __hip_bfloat16 h = __float2bfloat16(f);
    return *reinterpret_cast<unsigned short*>(&h);
}
DEV float bf2f(unsigned short u) {
    return __uint_as_float(((unsigned int)u) << 16);
}

DEV void gld16(const void* g, void* l) {
    __builtin_amdgcn_global_load_lds(
        (const __attribute__((address_space(1))) void*)g,
        (__attribute__((address_space(3))) void*)l, 16, 0, 0);
}

// ---------------------------------------------------------------------------
// z-batched fp32 -> bf16 convert of 3 equal-size weight tensors
// ---------------------------------------------------------------------------
__global__ __launch_bounds__(256) void f2b_conv3(
    const float* __restrict__ in0, const float* __restrict__ in1,
    const float* __restrict__ in2,
    unsigned short* __restrict__ o0, unsigned short* __restrict__ o1,
    unsigned short* __restrict__ o2, int n4)
{
    int i = blockIdx.x * 256 + threadIdx.x;
    if (i >= n4) return;
    const float* in = blockIdx.y == 0 ? in0 : (blockIdx.y == 1 ? in1 : in2);
    unsigned short* ob = blockIdx.y == 0 ? o0 : (blockIdx.y == 1 ? o1 : o2);
    float4_t v = *(const float4_t*)(in + (size_t)i * 4);
    ushort4_t o;
#pragma unroll
    for (int j = 0; j < 4; j++) o[j] = f2bf(v[j]);
    *(ushort4_t*)(ob + (size_t)i * 4) = o;
}

// ---------------------------------------------------------------------------
// 3 fused transposes (fp32 -> bf16, [R][C] -> [C][R]) in one flattened grid:
// blocks [0,6912): Wo 9216x768 ; [6912,9216): W1 768x3072 ; [9216,11520): W2
// ---------------------------------------------------------------------------
__global__ __launch_bounds__(256) void transpose3_f2b(
    const float* __restrict__ Wo, unsigned short* __restrict__ WOT,
    const float* __restrict__ W1, unsigned short* __restrict__ W1T,
    const float* __restrict__ W2, unsigned short* __restrict__ W2T)
{
    const int b = blockIdx.x;
    const float* in; unsigned short* ob; int R, C, bx, by;
    if (b < 6912)      { in = Wo; ob = WOT; R = 9216; C = 768;  bx = b % 24;          by = b / 24; }
    else if (b < 9216) { in = W1; ob = W1T; R = 768;  C = 3072; bx = (b-6912) % 96;   by = (b-6912) / 96; }
    else               { in = W2; ob = W2T; R = 3072; C = 768;  bx = (b-9216) % 24;   by = (b-9216) / 24; }
    __shared__ float tile[32][33];
    const int c0 = bx * 32, r0 = by * 32;
    const int tx = threadIdx.x & 31, ty = threadIdx.x >> 5;
#pragma unroll
    for (int i = 0; i < 32; i += 8)
        tile[ty + i][tx] = in[(size_t)(r0 + ty + i) * C + c0 + tx];
    __syncthreads();
#pragma unroll
    for (int i = 0; i < 32; i += 8)
        ob[(size_t)(c0 + ty + i) * R + r0 + tx] = f2bf(tile[tx][ty + i]);
}

// ---------------------------------------------------------------------------
// Fused small preps: blocks [0,36): U[h*768+d] = sum_e Wk[h,d,e]*bq[h,e]
//                    blocks [36,324): bvwo partials (96 chunks of 96 rows)
// ---------------------------------------------------------------------------
__global__ __launch_bounds__(256) void prep_misc(
    const float* __restrict__ Wk, const float* __restrict__ bq,
    float* __restrict__ U,
    const float* __restrict__ Wo, const float* __restrict__ bv,
    float* __restrict__ part)
{
    const int b = blockIdx.x;
    if (b < 36) {
        int i = b * 256 + threadIdx.x;   // 9216 total
        int h = i / 768;
        const float* wr = Wk + (size_t)i * 768;
        const float* bh = bq + (size_t)h * 768;
        float s = 0.f;
#pragma unroll 4
        for (int e = 0; e < 768; e++) s += wr[e] * bh[e];
        U[i] = s;
    } else {
        int bb = b - 36;                 // 288 blocks: (e-chunk 3) x (r-chunk 96)
        int e = (bb % 3) * 256 + threadIdx.x;
        int r0 = (bb / 3) * 96;
        float s = 0.f;
#pragma unroll 4
        for (int r = r0; r < r0 + 96; r++) s += bv[r] * Wo[(size_t)r * 768 + e];
        part[(size_t)(bb / 3) * 768 + e] = s;
    }
}

__global__ __launch_bounds__(256) void bvwo_final(
    const float* __restrict__ part, const float* __restrict__ bo, float* __restrict__ R)
{
    int e = blockIdx.x * 256 + threadIdx.x;   // 768
    float s = bo[e];
#pragma unroll
    for (int c = 0; c < 96; c++) s += part[(size_t)c * 768 + e];
    R[e] = s;
}

// ---------------------------------------------------------------------------
// LayerNorm over 768 cols, fp32 in -> bf16 out. One block (256 thr) per row.
// ---------------------------------------------------------------------------
__global__ __launch_bounds__(256) void layernorm768(
    const float* __restrict__ in, const float* __restrict__ g,
    const float* __restrict__ be, unsigned short* __restrict__ outb)
{
    const size_t rowoff = (size_t)blockIdx.x * 768;
    const float* xr = in + rowoff;
    const int t = threadIdx.x;
    float v0 = xr[t], v1 = xr[t + 256], v2 = xr[t + 512];
    __shared__ float red[8];
    float s = v0 + v1 + v2;
#pragma unroll
    for (int o = 32; o; o >>= 1) s += __shfl_down(s, o);
    if ((t & 63) == 0) red[t >> 6] = s;
    __syncthreads();
    float mu = (red[0] + red[1] + red[2] + red[3]) * (1.0f / 768.0f);
    float d0 = v0 - mu, d1 = v1 - mu, d2 = v2 - mu;
    float q = d0 * d0 + d1 * d1 + d2 * d2;
#pragma unroll
    for (int o = 32; o; o >>= 1) q += __shfl_down(q, o);
    if ((t & 63) == 0) red[4 + (t >> 6)] = q;
    __syncthreads();
    float rs = rsqrtf((red[4] + red[5] + red[6] + red[7]) * (1.0f / 768.0f) + 1e-5f);
    outb[rowoff + t]       = f2bf(d0 * rs * g[t]       + be[t]);
    outb[rowoff + t + 256] = f2bf(d1 * rs * g[t + 256] + be[t + 256]);
    outb[rowoff + t + 512] = f2bf(d2 * rs * g[t + 512] + be[t + 512]);
}

// ---------------------------------------------------------------------------
// Fused: x1 = res + colb + p0+p1+p2+p3 (write f32) THEN LayerNorm(x1) -> bf16.
// ---------------------------------------------------------------------------
__global__ __launch_bounds__(256) void reduce4_ln(
    const float* __restrict__ res, const float* __restrict__ colb,
    const float* __restrict__ p0, const float* __restrict__ p1,
    const float* __restrict__ p2, const float* __restrict__ p3,
    const float* __restrict__ g, const float* __restrict__ be,
    float* __restrict__ x1out, unsigned short* __restrict__ outb)
{
    const size_t rowoff = (size_t)blockIdx.x * 768;
    const int t = threadIdx.x;
    float v[3];
#pragma unroll
    for (int j = 0; j < 3; j++) {
        const size_t i = rowoff + t + j * 256;
        const int e = t + j * 256;
        v[j] = res[i] + colb[e] + (p0[i] + p1[i]) + (p2[i] + p3[i]);
        x1out[i] = v[j];
    }
    __shared__ float red[8];
    float s = v[0] + v[1] + v[2];
#pragma unroll
    for (int o = 32; o; o >>= 1) s += __shfl_down(s, o);
    if ((t & 63) == 0) red[t >> 6] = s;
    __syncthreads();
    float mu = (red[0] + red[1] + red[2] + red[3]) * (1.0f / 768.0f);
    float d0 = v[0] - mu, d1 = v[1] - mu, d2 = v[2] - mu;
    float q = d0 * d0 + d1 * d1 + d2 * d2;
#pragma unroll
    for (int o = 32; o; o >>= 1) q += __shfl_down(q, o);
    if ((t & 63) == 0) red[4 + (t >> 6)] = q;
    __syncthreads();
    float rs = rsqrtf((red[4] + red[5] + red[6] + red[7]) * (1.0f / 768.0f) + 1e-5f);
    outb[rowoff + t]       = f2bf(d0 * rs * g[t]       + be[t]);
    outb[rowoff + t + 256] = f2bf(d1 * rs * g[t + 256] + be[t + 256]);
    outb[rowoff + t + 512] = f2bf(d2 * rs * g[t + 512] + be[t + 512]);
}

// ---------------------------------------------------------------------------
// Softmax: one block per (b,s) row of SC[12288]; 4 waves x 3 segments of
// 1024. Wave-local shfl_xor reductions, no __syncthreads, 16B vector I/O.
// ---------------------------------------------------------------------------
__global__ __launch_bounds__(256) void softmax12x1024(unsigned short* __restrict__ p)
{
    unsigned short* row = p + (size_t)blockIdx.x * 12288;
    const int lane = threadIdx.x & 63, wave = threadIdx.x >> 6;
#pragma unroll
    for (int sgi = 0; sgi < 3; ++sgi) {
        unsigned short* seg = row + (wave * 3 + sgi) * 1024;
        ushort8_t u0 = *(const ushort8_t*)(seg + lane * 16);
        ushort8_t u1 = *(const ushort8_t*)(seg + lane * 16 + 8);
        float v[16];
        float m = -3.4e38f;
#pragma unroll
        for (int i = 0; i < 8; i++) { v[i] = bf2f(u0[i]); v[8 + i] = bf2f(u1[i]); }
#pragma unroll
        for (int i = 0; i < 16; i++) m = fmaxf(m, v[i]);
#pragma unroll
        for (int o = 32; o; o >>= 1) m = fmaxf(m, __shfl_xor(m, o));
        float s = 0.f;
#pragma unroll
        for (int i = 0; i < 16; i++) { v[i] = __expf(v[i] - m); s += v[i]; }
#pragma unroll
        for (int o = 32; o; o >>= 1) s += __shfl_xor(s, o);
        float inv = 1.f / s;
#pragma unroll
        for (int i = 0; i < 8; i++) { u0[i] = f2bf(v[i] * inv); u1[i] = f2bf(v[8 + i] * inv); }
        *(ushort8_t*)(seg + lane * 16) = u0;
        *(ushort8_t*)(seg + lane * 16 + 8) = u1;
    }
}

// ---------------------------------------------------------------------------
// dst[i] = res[i] + colb[i%768] + p0+p1+p2+p3   (f32, float4-vectorized)
// ---------------------------------------------------------------------------
__global__ __launch_bounds__(256) void reduce4(
    const float* __restrict__ res, const float* __restrict__ colb,
    const float* __restrict__ p0, const float* __restrict__ p1,
    const float* __restrict__ p2, const float* __restrict__ p3,
    float* __restrict__ dst)
{
    int i = blockIdx.x * 256 + threadIdx.x;         // float4 index
    float4_t r = *(const float4_t*)(res + (size_t)i * 4);
    float4_t a = *(const float4_t*)(p0 + (size_t)i * 4);
    float4_t b = *(const float4_t*)(p1 + (size_t)i * 4);
    float4_t c = *(const float4_t*)(p2 + (size_t)i * 4);
    float4_t d = *(const float4_t*)(p3 + (size_t)i * 4);
    float4_t cb = *(const float4_t*)(colb + (size_t)(i % 192) * 4);
    float4_t o;
#pragma unroll
    for (int j = 0; j < 4; j++) o[j] = r[j] + cb[j] + (a[j] + b[j]) + (c[j] + d[j]);
    *(float4_t*)(dst + (size_t)i * 4) = o;
}

enum { MODE_BF16 = 0, MODE_VT = 1, MODE_F32RES = 2 };

// ---------------------------------------------------------------------------
// gemm_bt (R8-proven): C[M,N] = A[M,K] * Bt[N,K]^T, bf16 in / f32 acc.
// 128x128 tile, BK=32, 4 waves, 2-buffer LDS (32 KiB), 2-phase pipeline
// with counted vmcnt(4), m204 XCD-bijective block swizzle.
// ---------------------------------------------------------------------------
template <int MODE, bool RELU>
__global__ __launch_bounds__(256) void gemm_bt(
    const unsigned short* __restrict__ A, int lda,
    const unsigned short* __restrict__ Bt, int ldb,
    void* __restrict__ Cout, int ldc,
    const float* __restrict__ bias,
    const float* __restrict__ res, int ldr,
    float scale, int K, int zdiv,
    long long sA1, long long sA2, long long sB1, long long sB2,
    long long sC1, long long sC2, long long sCJ, long long sBias)
{
    const unsigned gx = gridDim.x, gy = gridDim.y;
    const unsigned nwg = gx * gy * gridDim.z;
    unsigned lin = blockIdx.x + gx * (blockIdx.y + gy * blockIdx.z);
    {
        const unsigned q = nwg >> 3, r = nwg & 7;
        const unsigned xcd = lin & 7, idx = lin >> 3;
        lin = (xcd < r ? xcd * (q + 1) : r * (q + 1) + (xcd - r) * q) + idx;
    }
    const unsigned bx = lin % gx;
    const unsigned rem = lin / gx;
    const unsigned by = rem % gy, bz = rem / gy;

    const int z = (int)bz, zq = z / zdiv, zr = z % zdiv;
    A  += (size_t)zq * sA1 + (size_t)zr * sA2;
    Bt += (size_t)zq * sB1 + (size_t)zr * sB2;
    const size_t cOff = (size_t)zq * sC1 + (size_t)(zq >> 1) * sCJ + (size_t)zr * sC2;
    const float* biasp = bias ? bias + (size_t)zr * sBias : nullptr;

    const int m0 = by * 128, n0 = bx * 128;

    __shared__ __align__(16) unsigned short As[2][128 * 32];
    __shared__ __align__(16) unsigned short Bs[2][128 * 32];

    const int t = threadIdx.x, lane = t & 63, wave = t >> 6;
    const int wr = wave >> 1, wc = wave & 1;

    f32x4 zero = {0.f, 0.f, 0.f, 0.f};
    f32x4 acc[4][4];
#pragma unroll
    for (int i = 0; i < 4; i++)
#pragma unroll
        for (int j = 0; j < 4; j++) acc[i][j] = zero;

    const int r0 = t >> 2;              // staging row (t*16B)/64B
    const int ce = (t & 3) * 8;         // elem col within 32-elem row
    const int kq = (lane >> 4) * 8, rr = lane & 15;

    const int nt = K >> 5;              // K-tiles of 32 (always >= 2 here)

    auto stage = [&](int buf, int kt) {
        const int kk = kt * 32;
        const unsigned short* ga0 = A  + (size_t)(m0 + r0) * lda      + kk + ce;
        const unsigned short* ga1 = A  + (size_t)(m0 + 64 + r0) * lda + kk + ce;
        const unsigned short* gb0 = Bt + (size_t)(n0 + r0) * ldb      + kk + ce;
        const unsigned short* gb1 = Bt + (size_t)(n0 + 64 + r0) * ldb + kk + ce;
        char* la = (char*)(&As[buf][0]);
        char* lb = (char*)(&Bs[buf][0]);
        gld16(ga0, la + wave * 1024);
        gld16(ga1, la + 4096 + wave * 1024);
        gld16(gb0, lb + wave * 1024);
        gld16(gb1, lb + 4096 + wave * 1024);
    };

    stage(0, 0);
    stage(1, 1);
    asm volatile("s_waitcnt vmcnt(4)" ::: "memory");
    __builtin_amdgcn_s_barrier();

    int cur = 0;
    for (int kt = 0; kt < nt; ++kt) {
        bf16x8 a[4], b[4];
        const unsigned short* Ab = &As[cur][0];
        const unsigned short* Bb = &Bs[cur][0];
#pragma unroll
        for (int i = 0; i < 4; i++) {
            a[i] = *(const bf16x8*)(Ab + (wr * 64 + i * 16 + rr) * 32 + kq);
            b[i] = *(const bf16x8*)(Bb + (wc * 64 + i * 16 + rr) * 32 + kq);
        }
        asm volatile("s_waitcnt lgkmcnt(0)" ::: "memory");
        __builtin_amdgcn_s_barrier();
        if (kt + 2 < nt) stage(cur, kt + 2);

        __builtin_amdgcn_s_setprio(1);
#pragma unroll
        for (int i = 0; i < 4; i++)
#pragma unroll
            for (int j = 0; j < 4; j++)
                acc[i][j] = __builtin_amdgcn_mfma_f32_16x16x32_bf16(a[i], b[j], acc[i][j], 0, 0, 0);
        __builtin_amdgcn_s_setprio(0);

        if (kt + 2 < nt) asm volatile("s_waitcnt vmcnt(4)" ::: "memory");
        else             asm volatile("s_waitcnt vmcnt(0)" ::: "memory");
        __builtin_amdgcn_s_barrier();
        cur ^= 1;
    }

    // epilogue; C/D frag: col = lane&15, row = 4*(lane>>4) + reg   [m89]
    const int cr = (lane >> 4) * 4, cc = lane & 15;
#pragma unroll
    for (int i = 0; i < 4; i++) {
        const int rowb = m0 + wr * 64 + i * 16 + cr;
#pragma unroll
        for (int j = 0; j < 4; j++) {
            const int col = n0 + wc * 64 + j * 16 + cc;
            const float bv = biasp ? biasp[col] : 0.f;
            if (MODE == MODE_VT) {
                ushort4_t pk;
#pragma unroll
                for (int r = 0; r < 4; r++) {
                    float v = acc[i][j][r] * scale + bv;
                    if (RELU) v = fmaxf(v, 0.f);
                    pk[r] = f2bf(v);
                }
                *(ushort4_t*)((unsigned short*)Cout + cOff +
                              (size_t)col * ldc + rowb) = pk;
            } else {
#pragma unroll
                for (int r = 0; r < 4; r++) {
                    float v = acc[i][j][r] * scale + bv;
                    if (RELU) v = fmaxf(v, 0.f);
                    const int row = rowb + r;
                    if (MODE == MODE_BF16) {
                        ((unsigned short*)Cout)[cOff + (size_t)row * ldc + col] = f2bf(v);
                    } else {
                        float ov = res ? v + res[(size_t)row * ldr + col] : v;
                        ((float*)Cout)[cOff + (size_t)row * ldc + col] = ov;
                    }
                }
            }
        }
    }
}

__global__ void ws_too_small(float* o, float v) { o[0] = v; }

// ---------------------------------------------------------------------------
extern "C" void kernel_launch(void* const* d_in, const int* in_sizes, int n_in,
                              void* d_out, int out_size, void* d_ws, size_t ws_size,
                              hipStream_t stream)
{
    const float* x   = (const float*)d_in[0];
    const float* Wq  = (const float*)d_in[1];
    const float* bq  = (const float*)d_in[2];
    const float* Wk  = (const float*)d_in[3];
    const float* Wv  = (const float*)d_in[5];
    const float* bv  = (const float*)d_in[6];
    const float* Wo  = (const float*)d_in[7];
    const float* bo  = (const float*)d_in[8];
    const float* W1  = (const float*)d_in[9];
    const float* b1  = (const float*)d_in[10];
    const float* W2  = (const float*)d_in[11];
    const float* b2  = (const float*)d_in[12];
    const float* g1  = (const float*)d_in[13];
    const float* be1 = (const float*)d_in[14];
    const float* g2  = (const float*)d_in[15];
    const float* be2 = (const float*)d_in[16];
    float* out = (float*)d_out;

    // --- workspace layout (peak 258,284,544 B < 256 MiB) ---
    char* ws = (char*)d_ws;
    unsigned short* W1T  = (unsigned short*)(ws);             // [3072][768]
    unsigned short* W2T  = (unsigned short*)(ws + 4718592);   // [768][3072]
    unsigned short* WQKT = (unsigned short*)(ws + 9437184);   // [12][768(d')][768(d)]
    unsigned short* WVOT = (unsigned short*)(ws + 23592960);  // [12][768(e)][768(d)]
    float*          U    = (float*)(ws + 37748736);           // [12][768]
    float*          BVWO = (float*)(ws + 37785600);           // [768]
    float*          PART = (float*)(ws + 37788672);           // [96][768]
    unsigned short* HB   = (unsigned short*)(ws + 38083584);  // [4096][768] LN1
    float*          X1   = (float*)(ws + 44375040);           // [4096][768] f32
    unsigned short* TB   = (unsigned short*)(ws + 56957952);  // [4][12][1024][768]
    unsigned short* SC   = (unsigned short*)(ws + 132455424); // [4096][12288]
    const size_t NEED = 258284544;

    if (ws_size < NEED) {   // diagnostic: absmax in the log equals ws_size
        hipMemsetAsync(d_out, 0, (size_t)out_size * sizeof(float), stream);
        ws_too_small<<<1, 1, 0, stream>>>(out, (float)ws_size);
        return;
    }

    // overlays (time-disjoint):
    unsigned short* VOT = TB;                                  // [4][768][12288] after softmax
    // split-K f32 partials [4096][768] x4: over dead WQKT/WVOT + tail
    float* P0 = (float*)(ws + 9437184);
    float* P1 = (float*)(ws + 22020096);
    float* P2 = (float*)(ws + 233118720);
    float* P3 = (float*)(ws + 245701632);
    // cOff: c*3145728 + (c>>1)*49628928 floats from P0 base
    unsigned short* WqB = (unsigned short*)(ws + 132455424);   // prep over not-yet-live SC
    unsigned short* WkB = (unsigned short*)(ws + 146611200);
    unsigned short* WvB = (unsigned short*)(ws + 160766976);
    unsigned short* WOT = (unsigned short*)(ws + 174922752);   // [768][9216]
    unsigned short* H2B = (unsigned short*)(ws + 56957952);    // post-attn over TB/VOT
    unsigned short* FFN = (unsigned short*)(ws + 63249408);    // [4096][3072]

    // ---- weight preparation ----
    f2b_conv3<<<dim3(6912, 3), 256, 0, stream>>>(Wq, Wk, Wv, WqB, WkB, WvB, 1769472);
    transpose3_f2b<<<11520, 256, 0, stream>>>(Wo, WOT, W1, W1T, W2, W2T);

    // WQKT[h][d'][d] = sum_m Wk[h,d',m] Wq[h,d,m]
    gemm_bt<MODE_BF16, false><<<dim3(6, 6, 12), 256, 0, stream>>>(
        WkB, 768, WqB, 768, WQKT, 768, nullptr, nullptr, 0, 1.0f, 768, 12,
        0, 589824, 0, 589824, 0, 589824, 0, 0);
    // WVOT[h][e][d] = sum_m Wo[h*768+m,e] Wv[h,d,m]
    gemm_bt<MODE_BF16, false><<<dim3(6, 6, 12), 256, 0, stream>>>(
        WOT, 9216, WvB, 768, WVOT, 768, nullptr, nullptr, 0, 1.0f, 768, 12,
        0, 768, 0, 589824, 0, 589824, 0, 0);

    prep_misc<<<324, 256, 0, stream>>>(Wk, bq, U, Wo, bv, PART);
    bvwo_final<<<3, 256, 0, stream>>>(PART, bo, BVWO);

    layernorm768<<<4096, 256, 0, stream>>>(x, g1, be1, HB);

    // T[b][h][s][d'] = LN1_b @ Wqk_h + u_h        (zq=b, zr=h)
    gemm_bt<MODE_BF16, false><<<dim3(6, 8, 48), 256, 0, stream>>>(
        HB, 768, WQKT, 768, TB, 768, U, nullptr, 0, 1.0f, 768, 12,
        786432, 0, 0, 589824, 9437184, 786432, 0, 768);

    // scores[b*1024+s][h*1024+t] = scale * T_bh @ LN1_b^T
    gemm_bt<MODE_BF16, false><<<dim3(8, 8, 48), 256, 0, stream>>>(
        TB, 768, HB, 768, SC, 12288, nullptr, nullptr, 0,
        0.03608439182435161f, 768, 12,
        9437184, 786432, 786432, 0, 12582912, 1024, 0, 0);

    softmax12x1024<<<4096, 256, 0, stream>>>(SC);

    // VOT[b][e][h*1024+t] = (LN1_b @ Wvo_h)^T     (transposed store; over TB)
    gemm_bt<MODE_VT, false><<<dim3(6, 8, 48), 256, 0, stream>>>(
        HB, 768, WVOT, 768, VOT, 12288, nullptr, nullptr, 0, 1.0f, 768, 12,
        786432, 0, 0, 589824, 9437184, 1024, 0, 0);

    // PV split-K 4: P{c}[b*1024+s][e] = P_chunk @ VO_chunk  (zq=c, zr=b)
    gemm_bt<MODE_F32RES, false><<<dim3(6, 8, 16), 256, 0, stream>>>(
        SC, 12288, VOT, 12288, P0, 768, nullptr, nullptr, 0, 1.0f, 3072, 4,
        3072, 12582912, 3072, 9437184, 3145728, 786432, 49628928, 0);

    // x1 = x + BVWO + P0..P3 ; H2 = LN2(x1)   (fused)
    reduce4_ln<<<4096, 256, 0, stream>>>(x, BVWO, P0, P1, P2, P3, g2, be2, X1, H2B);

    // ffn1 = relu(h2 @ W1 + b1)
    gemm_bt<MODE_BF16, true><<<dim3(24, 32, 1), 256, 0, stream>>>(
        H2B, 768, W1T, 768, FFN, 3072, b1, nullptr, 0, 1.0f, 768, 1,
        0, 0, 0, 0, 0, 0, 0, 0);

    // FFN2 split-K 4: Q{c} = ffn1_chunk @ W2_chunk   (zq=c)
    gemm_bt<MODE_F32RES, false><<<dim3(6, 32, 4), 256, 0, stream>>>(
        FFN, 3072, W2T, 3072, P0, 768, nullptr, nullptr, 0, 1.0f, 768, 1,
        768, 0, 768, 0, 3145728, 0, 49628928, 0);

    // out = x1 + b2 + Q0..Q3
    reduce4<<<3072, 256, 0, stream>>>(X1, b2, P0, P1, P2, P3, out);
}